// Round 1
// baseline (345.476 us; speedup 1.0000x reference)
//
#include <hip/hip_runtime.h>

// Chamfer distance, B=16, N=M=4096, D=3.
// dist(i,j) = n1 + n2 - 2*x1.x2 as ONE bf16 MFMA per 32x32 tile (norms folded
// into padded K slots, hi/lo bf16 split => exact-grade).
// R5 (fusion): compute each batch's distance matrix ONCE.
//  - row-min: elementwise v_min3 fold into rm0/rm1 registers (as before)
//  - col-min: per col-tile min3-chain over both row-tile accumulators +
//    shfl_xor(32) half-merge -> per-wave LDS colw (each entry written exactly
//    once, no atomics) -> block merge -> colpart partial in gmem
//  - halves MFMA count, halves Bfr stream, halves prepack work
//  - launch_bounds (256,3): VGPR cap 168 fits the 4-live-accumulator quad
//    (at (256,4)/cap-128 the ~160-reg live set forced serialization/spill)
//  - no global atomicMin: rowpart/colpart partials + 64-block reduce

typedef __attribute__((ext_vector_type(8))) __bf16 bf16x8;
typedef __attribute__((ext_vector_type(16))) float f32x16;

#define PTS 4096
#define TILES 128  // PTS/32
#define NB 16

__device__ __forceinline__ unsigned f2bf(float f) {
  unsigned u = __float_as_uint(f);
  return (u + 0x7FFFu + ((u >> 16) & 1u)) >> 16;  // RNE bf16 bits
}
__device__ __forceinline__ float bf2f(unsigned s) {
  return __uint_as_float(s << 16);
}
__device__ __forceinline__ unsigned pk(unsigned lo, unsigned hi) {
  return (lo & 0xFFFFu) | (hi << 16);
}

// ---- prepack x2-side (column) fragments + zero out ----
// Bfr[((b*TILES+t)*2+h)*32 + l31]
// B k-vec: w0=[Hx Hy Hz Lx Ly Lz Hx Hy]  w1=[Hz nh nl 1 1 0 0 0], H,L split -2q.
__global__ __launch_bounds__(256) void prepack_b(const float* __restrict__ x2,
                                                 uint4* __restrict__ Bfr,
                                                 float* __restrict__ out) {
  const int id = blockIdx.x * 256 + threadIdx.x;  // NB*PTS = 65536
  if (id < NB) out[id] = 0.f;                     // reduce uses atomicAdd
  const int b = id >> 12;
  const int j = id & (PTS - 1);
  const float* q = x2 + (size_t)(b * PTS + j) * 3;
  const float x = q[0], y = q[1], z = q[2];
  const float sx = -2.f * x, sy = -2.f * y, sz = -2.f * z;
  const unsigned Hx = f2bf(sx), Hy = f2bf(sy), Hz = f2bf(sz);
  const unsigned Lx = f2bf(sx - bf2f(Hx));
  const unsigned Ly = f2bf(sy - bf2f(Hy));
  const unsigned Lz = f2bf(sz - bf2f(Hz));
  const float n = fmaf(x, x, fmaf(y, y, z * z));
  const unsigned nh = f2bf(n), nl = f2bf(n - bf2f(nh));
  const unsigned one = 0x3F80u;
  uint4 w0, w1;
  w0.x = pk(Hx, Hy); w0.y = pk(Hz, Lx); w0.z = pk(Ly, Lz); w0.w = pk(Hx, Hy);
  w1.x = pk(Hz, nh); w1.y = pk(nl, one); w1.z = pk(one, 0u); w1.w = 0u;
  uint4* base = Bfr + ((size_t)(b * TILES + (j >> 5)) * 2) * 32 + (j & 31);
  base[0]  = w0;   // half 0 (k 0..7)
  base[32] = w1;   // half 1 (k 8..15)
}

// ---- main: 256 threads (4 waves) share one 32-KB col stream (L1 reuse).
// grid.x = 64 slices (b,cq) -> XCD = x%8 pins slice stream to one L2.
// grid.y = 16 row-groups of 256 rows.  One pass: row-min AND col-min.
__global__ __launch_bounds__(256, 3) void chamfer_main(
    const float* __restrict__ x1, const uint4* __restrict__ Bfr,
    float* __restrict__ rowpart, float* __restrict__ colpart) {
  const int s  = blockIdx.x;           // (b, col-quarter)
  const int b  = s >> 2;
  const int cq = s & 3;
  const int rg = blockIdx.y;           // row-group: 8 row-tiles

  const int tid  = threadIdx.x;
  const int lane = tid & 63;
  const int half = lane >> 5;          // K-half this lane supplies to MFMA
  const int l31  = lane & 31;
  const int wave = tid >> 6;

  __shared__ float colw[4][1024];      // per-wave col partials (16 KB)

  // --- build A fragments from raw points (row tiles t0, t0+1) ---
  // A k-vec: w0=[hx hy hz hx hy hz lx ly]  w1=[lz 1 1 nh nl 0 0 0]
  const int t0 = rg * 8 + wave * 2;
  bf16x8 af[2];
#pragma unroll
  for (int rr = 0; rr < 2; ++rr) {
    const int r = (t0 + rr) * 32 + l31;
    const float* p = x1 + (size_t)(b * PTS + r) * 3;
    const float x = p[0], y = p[1], zc = p[2];
    const unsigned hx = f2bf(x), hy = f2bf(y), hz = f2bf(zc);
    const unsigned lx = f2bf(x - bf2f(hx));
    const unsigned ly = f2bf(y - bf2f(hy));
    const unsigned lz = f2bf(zc - bf2f(hz));
    const float n = fmaf(x, x, fmaf(y, y, zc * zc));
    const unsigned nh = f2bf(n), nl = f2bf(n - bf2f(nh));
    const unsigned one = 0x3F80u;
    uint4 w0, w1;
    w0.x = pk(hx, hy); w0.y = pk(hz, hx); w0.z = pk(hy, hz); w0.w = pk(lx, ly);
    w1.x = pk(lz, one); w1.y = pk(one, nh); w1.z = pk(nl, 0u); w1.w = 0u;
    uint4 w;
    w.x = half ? w1.x : w0.x; w.y = half ? w1.y : w0.y;
    w.z = half ? w1.z : w0.z; w.w = half ? w1.w : w0.w;
    af[rr] = *(const bf16x8*)&w;
  }
  const bf16x8 af0 = af[0], af1 = af[1];

  f32x16 zero;
#pragma unroll
  for (int e = 0; e < 16; ++e) zero[e] = 0.f;

  float rm0[16], rm1[16];
#pragma unroll
  for (int e = 0; e < 16; ++e) { rm0[e] = 3.0e38f; rm1[e] = 3.0e38f; }

  // --- stream this col-quarter's 32 tiles; 8-slot ring, 4+ loads in flight ---
  const uint4* bp = Bfr + ((size_t)(b * TILES + cq * 32) * 2) * 32;
  const int off = half * 32 + l31;  // within a tile: h*32 + col
  bf16x8 buf[8];
#pragma unroll
  for (int t = 0; t < 4; ++t) buf[t] = *(const bf16x8*)&bp[t * 64 + off];

#pragma unroll 2
  for (int g = 0; g < 8; ++g) {
    const int cur = (g & 1) * 4;
    const int nxt = ((g + 1) & 1) * 4;
    const int pf  = ((g + 1) & 7) * 4;  // wrap: last prefetch redundant, safe
#pragma unroll
    for (int t = 0; t < 4; ++t)
      buf[nxt + t] = *(const bf16x8*)&bp[(pf + t) * 64 + off];
#pragma unroll
    for (int t = 0; t < 4; t += 2) {
      const bf16x8 b0 = buf[cur + t], b1 = buf[cur + t + 1];
      const f32x16 a00 =
          __builtin_amdgcn_mfma_f32_32x32x16_bf16(af0, b0, zero, 0, 0, 0);
      const f32x16 a01 =
          __builtin_amdgcn_mfma_f32_32x32x16_bf16(af0, b1, zero, 0, 0, 0);
      const f32x16 a10 =
          __builtin_amdgcn_mfma_f32_32x32x16_bf16(af1, b0, zero, 0, 0, 0);
      const f32x16 a11 =
          __builtin_amdgcn_mfma_f32_32x32x16_bf16(af1, b1, zero, 0, 0, 0);
      // row-min folds (v_min3): pair over col-tiles
#pragma unroll
      for (int e = 0; e < 16; ++e)
        rm0[e] = fminf(fminf(a00[e], a01[e]), rm0[e]);
#pragma unroll
      for (int e = 0; e < 16; ++e)
        rm1[e] = fminf(fminf(a10[e], a11[e]), rm1[e]);
      // col-min chains (v_min3): pair over row-tiles, 2 ILP chains each
      float c0a = fminf(a00[0], a10[0]), c0b = fminf(a00[1], a10[1]);
      float c1a = fminf(a01[0], a11[0]), c1b = fminf(a01[1], a11[1]);
#pragma unroll
      for (int e = 2; e < 16; e += 2) {
        c0a = fminf(c0a, fminf(a00[e], a10[e]));
        c0b = fminf(c0b, fminf(a00[e + 1], a10[e + 1]));
        c1a = fminf(c1a, fminf(a01[e], a11[e]));
        c1b = fminf(c1b, fminf(a01[e + 1], a11[e + 1]));
      }
      float c0 = fminf(c0a, c0b);
      float c1 = fminf(c1a, c1b);
      c0 = fminf(c0, __shfl_xor(c0, 32));  // merge the two row-halves
      c1 = fminf(c1, __shfl_xor(c1, 32));
      if (half == 0) {
        colw[wave][(g * 4 + t) * 32 + l31]     = c0;
        colw[wave][(g * 4 + t + 1) * 32 + l31] = c1;
      }
    }
  }

  // --- per-row min over this wave's 32 cols, direct store (no atomics) ---
  // C/D layout: col = lane&31, row_local = (e&3) + 8*(e>>2) + 4*half.
  float* rb = rowpart + (size_t)(b * 4 + cq) * PTS + t0 * 32;
#pragma unroll
  for (int e = 0; e < 16; ++e) {
    float v = rm0[e];
    v = fminf(v, __shfl_xor(v, 1));
    v = fminf(v, __shfl_xor(v, 2));
    v = fminf(v, __shfl_xor(v, 4));
    v = fminf(v, __shfl_xor(v, 8));
    v = fminf(v, __shfl_xor(v, 16));
    if (l31 == e) rb[(e & 3) + 8 * (e >> 2) + 4 * half] = v;
  }
#pragma unroll
  for (int e = 0; e < 16; ++e) {
    float v = rm1[e];
    v = fminf(v, __shfl_xor(v, 1));
    v = fminf(v, __shfl_xor(v, 2));
    v = fminf(v, __shfl_xor(v, 4));
    v = fminf(v, __shfl_xor(v, 8));
    v = fminf(v, __shfl_xor(v, 16));
    if (l31 == e) rb[32 + (e & 3) + 8 * (e >> 2) + 4 * half] = v;
  }

  // --- merge 4 waves' col partials -> colpart[b][rg][col] ---
  __syncthreads();
  float* cb = colpart + (size_t)(b * 16 + rg) * PTS + cq * 1024;
  for (int c = tid; c < 1024; c += 256)
    cb[c] = fminf(fminf(colw[0][c], colw[1][c]),
                  fminf(colw[2][c], colw[3][c]));
}

// ---- reduce: out[b] = (sum_r min_cq rowpart + sum_c min_rg colpart) / PTS ----
// 64 blocks: (b, quarter).  Clamp-to-0 after the min (commutes with fmax).
__global__ __launch_bounds__(256) void reduce_out(
    const float* __restrict__ rowpart, const float* __restrict__ colpart,
    float* __restrict__ out) {
  const int b = blockIdx.x >> 2;
  const int seg = blockIdx.x & 3;
  const int tid = threadIdx.x;
  float s = 0.f;
  const float* rp = rowpart + (size_t)b * 4 * PTS + seg * 1024;
  for (int r = tid; r < 1024; r += 256) {
    float m = fminf(fminf(rp[r], rp[PTS + r]),
                    fminf(rp[2 * PTS + r], rp[3 * PTS + r]));
    s += fmaxf(m, 0.f);
  }
  const float* cp = colpart + (size_t)b * 16 * PTS + seg * 1024;
  for (int c = tid; c < 1024; c += 256) {
    float m = cp[c];
#pragma unroll
    for (int k = 1; k < 16; ++k) m = fminf(m, cp[(size_t)k * PTS + c]);
    s += fmaxf(m, 0.f);
  }
  s += __shfl_xor(s, 1);
  s += __shfl_xor(s, 2);
  s += __shfl_xor(s, 4);
  s += __shfl_xor(s, 8);
  s += __shfl_xor(s, 16);
  s += __shfl_xor(s, 32);
  __shared__ float acc[4];
  if ((tid & 63) == 0) acc[tid >> 6] = s;
  __syncthreads();
  if (tid == 0)
    atomicAdd(&out[b], (acc[0] + acc[1] + acc[2] + acc[3]) * (1.f / PTS));
}

extern "C" void kernel_launch(void* const* d_in, const int* in_sizes, int n_in,
                              void* d_out, int out_size, void* d_ws,
                              size_t ws_size, hipStream_t stream) {
  const float* x1 = (const float*)d_in[0];
  const float* x2 = (const float*)d_in[1];
  float* out = (float*)d_out;

  // ws layout: Bfr 2 MB | rowpart 1 MB | colpart 4 MB
  uint4* Bfr = (uint4*)d_ws;
  float* rowpart = (float*)((char*)d_ws + ((size_t)2 << 20));
  float* colpart = (float*)((char*)d_ws + ((size_t)3 << 20));

  prepack_b<<<(NB * PTS) / 256, 256, 0, stream>>>(x2, Bfr, out);
  dim3 grid(64, NB);  // x = (b,cq) slice -> XCD = x%8 ; y = row-group
  chamfer_main<<<grid, 256, 0, stream>>>(x1, Bfr, rowpart, colpart);
  reduce_out<<<64, 256, 0, stream>>>(rowpart, colpart, out);
}